// Round 1
// baseline (65.816 us; speedup 1.0000x reference)
//
#include <hip/hip_runtime.h>

#define N_IN    256
#define N_EVAL  1088
#define TOTALW  (N_IN + N_EVAL)   // 1344
#define DEG     32
#define TILE_B  8
#define VSTRIDE (TOTALW + 1)      // 1345, odd stride to decorrelate banks across rows
#define NTHREADS 256

__global__ __launch_bounds__(NTHREADS) void neat_eval(
    const float* __restrict__ x, const float* __restrict__ w,
    const float* __restrict__ bias, const float* __restrict__ resp,
    const int* __restrict__ src, float* __restrict__ out)
{
    __shared__ float vals[TILE_B * VSTRIDE];   // 43,040 B
    const int tid = threadIdx.x;
    const int b0  = blockIdx.x * TILE_B;

    // Stage x tile: TILE_B x 256, coalesced (consecutive tid -> consecutive col)
    #pragma unroll
    for (int i = 0; i < (TILE_B * N_IN) / NTHREADS; ++i) {
        int idx = tid + i * NTHREADS;
        int b = idx >> 8;          // /256
        int c = idx & 255;
        vals[b * VSTRIDE + c] = x[(size_t)(b0 + b) * N_IN + c];
    }
    __syncthreads();

    const int sizes[5] = {256, 256, 256, 256, 64};
    int row = 0;
    int outoff = N_IN;
    #pragma unroll
    for (int li = 0; li < 5; ++li) {
        const int sz = sizes[li];           // compile-time after unroll
        const int tasks = sz * TILE_B;
        for (int task = tid; task < tasks; task += NTHREADS) {
            // neuron-fastest: consecutive lanes -> different neurons, same batch row
            int n = task % sz;
            int b = task / sz;
            int gr = row + n;
            const int4*   s4 = (const int4*)(src + (size_t)gr * DEG);
            const float4* w4 = (const float4*)(w   + (size_t)gr * DEG);
            const float* vrow = vals + b * VSTRIDE;
            float acc = 0.f;
            #pragma unroll
            for (int k = 0; k < DEG / 4; ++k) {
                int4   i4 = s4[k];
                float4 wv = w4[k];
                acc += vrow[i4.x] * wv.x;
                acc += vrow[i4.y] * wv.y;
                acc += vrow[i4.z] * wv.z;
                acc += vrow[i4.w] * wv.w;
            }
            float o = bias[gr] + resp[gr] * acc;
            vals[b * VSTRIDE + outoff + n] = fmaxf(o, 0.f);
        }
        __syncthreads();
        row += sz;
        outoff += sz;
    }

    // Write final 64 columns (layer 5 output), coalesced
    #pragma unroll
    for (int i = tid; i < TILE_B * 64; i += NTHREADS) {
        int b = i >> 6;
        int c = i & 63;
        out[(size_t)(b0 + b) * 64 + c] = vals[b * VSTRIDE + (TOTALW - 64) + c];
    }
}

extern "C" void kernel_launch(void* const* d_in, const int* in_sizes, int n_in,
                              void* d_out, int out_size, void* d_ws, size_t ws_size,
                              hipStream_t stream) {
    const float* x    = (const float*)d_in[0];
    const float* w    = (const float*)d_in[1];
    const float* bias = (const float*)d_in[2];
    const float* resp = (const float*)d_in[3];
    const int*   src  = (const int*)d_in[4];
    float* out = (float*)d_out;

    const int batch = in_sizes[0] / N_IN;        // 8192
    const int grid  = batch / TILE_B;            // 1024 blocks
    neat_eval<<<grid, NTHREADS, 0, stream>>>(x, w, bias, resp, src, out);
}

// Round 2
// 44.681 us; speedup vs baseline: 1.4730x; 1.4730x over previous
//
#include <hip/hip_runtime.h>

#define N_IN    256
#define N_EVAL  1088
#define TOTALW  (N_IN + N_EVAL)   // 1344
#define DEG     32
#define TILE_B  8
#define NTHREADS 256

// Transposed LDS layout: float index for (col c, batch b) = (c*8 + b),
// XOR-swizzled in bits [4:2] so the 16B granules hash over all 8 bank-groups.
__device__ __forceinline__ int swz_base(int c) {
    return (c << 3) ^ (((c >> 2) & 7) << 2);
}

__device__ __forceinline__ void colacc(const float* __restrict__ vals, int c, float wv,
                                       float4& accA, float4& accB) {
    int f = swz_base(c);
    const float4 a = *(const float4*)(vals + f);        // rows 0..3
    const float4 b = *(const float4*)(vals + (f ^ 4));  // rows 4..7
    accA.x = fmaf(a.x, wv, accA.x); accA.y = fmaf(a.y, wv, accA.y);
    accA.z = fmaf(a.z, wv, accA.z); accA.w = fmaf(a.w, wv, accA.w);
    accB.x = fmaf(b.x, wv, accB.x); accB.y = fmaf(b.y, wv, accB.y);
    accB.z = fmaf(b.z, wv, accB.z); accB.w = fmaf(b.w, wv, accB.w);
}

__global__ __launch_bounds__(NTHREADS) void neat_eval(
    const float* __restrict__ x, const float* __restrict__ w,
    const float* __restrict__ bias, const float* __restrict__ resp,
    const int* __restrict__ src, float* __restrict__ out)
{
    __shared__ float vals[TILE_B * TOTALW];   // 43,008 B, transposed+swizzled
    const int tid = threadIdx.x;
    const int b0  = blockIdx.x * TILE_B;

    // Stage x tile transposed: read coalesced float4 along columns, scatter to LDS
    #pragma unroll
    for (int i = 0; i < 2; ++i) {
        int idx = tid + i * NTHREADS;      // 0..511
        int cq  = idx & 63;                // column quad
        int b   = idx >> 6;                // batch row 0..7
        float4 x4 = *(const float4*)(x + (size_t)(b0 + b) * N_IN + cq * 4);
        int badj = b & 3, bx = b & 4;
        vals[((swz_base(cq * 4 + 0)) ^ bx) + badj] = x4.x;
        vals[((swz_base(cq * 4 + 1)) ^ bx) + badj] = x4.y;
        vals[((swz_base(cq * 4 + 2)) ^ bx) + badj] = x4.z;
        vals[((swz_base(cq * 4 + 3)) ^ bx) + badj] = x4.w;
    }
    __syncthreads();

    int row = 0;
    int outoff = N_IN;
    #pragma unroll
    for (int li = 0; li < 5; ++li) {
        const int sz = (li < 4) ? 256 : 64;
        for (int n = tid; n < sz; n += NTHREADS) {
            const int gr = row + n;
            const int4*   s4 = (const int4*)(src + (size_t)gr * DEG);
            const float4* w4 = (const float4*)(w   + (size_t)gr * DEG);
            float4 accA = {0.f, 0.f, 0.f, 0.f};
            float4 accB = {0.f, 0.f, 0.f, 0.f};
            #pragma unroll
            for (int k = 0; k < DEG / 4; ++k) {
                int4   i4 = s4[k];
                float4 wv = w4[k];
                colacc(vals, i4.x, wv.x, accA, accB);
                colacc(vals, i4.y, wv.y, accA, accB);
                colacc(vals, i4.z, wv.z, accA, accB);
                colacc(vals, i4.w, wv.w, accA, accB);
            }
            const float bb = bias[gr], rr = resp[gr];
            accA.x = fmaxf(fmaf(rr, accA.x, bb), 0.f);
            accA.y = fmaxf(fmaf(rr, accA.y, bb), 0.f);
            accA.z = fmaxf(fmaf(rr, accA.z, bb), 0.f);
            accA.w = fmaxf(fmaf(rr, accA.w, bb), 0.f);
            accB.x = fmaxf(fmaf(rr, accB.x, bb), 0.f);
            accB.y = fmaxf(fmaf(rr, accB.y, bb), 0.f);
            accB.z = fmaxf(fmaf(rr, accB.z, bb), 0.f);
            accB.w = fmaxf(fmaf(rr, accB.w, bb), 0.f);
            int fo = swz_base(outoff + n);
            *(float4*)(vals + fo)       = accA;
            *(float4*)(vals + (fo ^ 4)) = accB;
        }
        __syncthreads();
        row += sz;
        outoff += sz;
    }

    // Write final 64 columns, coalesced on global
    #pragma unroll
    for (int i = 0; i < 2; ++i) {
        int idx = tid + i * NTHREADS;      // 0..511
        int c = idx & 63;
        int b = idx >> 6;
        int oc = TOTALW - 64 + c;
        float v = vals[((swz_base(oc)) ^ (b & 4)) + (b & 3)];
        out[(size_t)(b0 + b) * 64 + c] = v;
    }
}

extern "C" void kernel_launch(void* const* d_in, const int* in_sizes, int n_in,
                              void* d_out, int out_size, void* d_ws, size_t ws_size,
                              hipStream_t stream) {
    const float* x    = (const float*)d_in[0];
    const float* w    = (const float*)d_in[1];
    const float* bias = (const float*)d_in[2];
    const float* resp = (const float*)d_in[3];
    const int*   src  = (const int*)d_in[4];
    float* out = (float*)d_out;

    const int batch = in_sizes[0] / N_IN;        // 8192
    const int grid  = batch / TILE_B;            // 1024 blocks
    neat_eval<<<grid, NTHREADS, 0, stream>>>(x, w, bias, resp, src, out);
}